// Round 3
// baseline (276.506 us; speedup 1.0000x reference)
//
#include <hip/hip_runtime.h>

#define NCLS 19
#define HW (512 * 512)
#define NB 8
#define NPIX (NB * HW)
#define BLOCKS 1024
#define THREADS 256
#define TOT (BLOCKS * THREADS)   // 262144 == HW: thread gid handles pixel hw=gid in all 8 images

// ws layout (floats): [0]=sum_wnll [1]=focal_sum
//                     [2..20]=intersection [21..39]=prob_sums [40..58]=counts

__global__ __launch_bounds__(THREADS, 4)
void focal_dice_main(const float* __restrict__ logits,
                     const int*   __restrict__ target,
                     const float* __restrict__ cw,
                     const float* __restrict__ fa,
                     float*       __restrict__ ws)
{
    __shared__ float sh_cw[NCLS], sh_fa[NCLS];
    __shared__ float sh_inter[NCLS], sh_cnt[NCLS], sh_psum[NCLS];
    __shared__ float sh_scal[2];

    const int tid = threadIdx.x;
    if (tid < NCLS) {
        sh_cw[tid] = cw[tid];
        sh_fa[tid] = fa[tid];
        sh_inter[tid] = 0.f; sh_cnt[tid] = 0.f; sh_psum[tid] = 0.f;
    }
    if (tid < 2) sh_scal[tid] = 0.f;
    __syncthreads();

    const unsigned gid = blockIdx.x * (unsigned)THREADS + (unsigned)tid;  // hw index

    // thread-persistent accumulators
    float psum[NCLS];
#pragma unroll
    for (int c = 0; c < NCLS; ++c) psum[c] = 0.f;
    float v_wnll = 0.f, v_foc = 0.f;

    for (int b = 0; b < NB; ++b) {
        const float* lp = logits + (size_t)b * (NCLS * (size_t)HW) + gid;
        const int t = target[(size_t)b * HW + gid];

        // ---- load 19 class logits for this pixel (scalar -> 19 VGPRs, no spill) ----
        float x[NCLS];
#pragma unroll
        for (int c = 0; c < NCLS; ++c)
            x[c] = lp[(size_t)c * HW];

        // target logit via gathered load (L1-hit: lines just fetched above)
        const float xt = lp[(size_t)t * HW];

        // ---- max over classes ----
        float m = x[0];
#pragma unroll
        for (int c = 1; c < NCLS; ++c) m = fmaxf(m, x[c]);

        // ---- exp + sum, keep e_c in x[] ----
        float s = 0.f;
#pragma unroll
        for (int c = 0; c < NCLS; ++c) {
            const float e = __expf(x[c] - m);
            s += e;
            x[c] = e;
        }
        const float rs = __builtin_amdgcn_rcpf(s);

        // ---- per-class prob sums accumulate in registers ----
#pragma unroll
        for (int c = 0; c < NCLS; ++c) psum[c] += x[c] * rs;

        // ---- per-pixel terms ----
        const float et  = __expf(xt - m);
        const float pt  = et * rs;                 // unclamped: used for dice intersection
        const float lpt = (xt - m) - __logf(s);    // log p_t
        const float ptc = fmaxf(pt, 1e-8f);        // clamped for focal factor

        const float w = sh_cw[t];
        const float a = sh_fa[t];
        v_wnll -= w * lpt;
        const float o = 1.f - ptc;
        v_foc  -= a * o * o * lpt;

        atomicAdd(&sh_inter[t], pt);
        atomicAdd(&sh_cnt[t], 1.f);
    }

    // ---- once-per-thread wave butterfly reductions ----
    auto wsum = [](float v) {
        v += __shfl_xor(v, 1);
        v += __shfl_xor(v, 2);
        v += __shfl_xor(v, 4);
        v += __shfl_xor(v, 8);
        v += __shfl_xor(v, 16);
        v += __shfl_xor(v, 32);
        return v;
    };

    const int lane = tid & 63;
    v_wnll = wsum(v_wnll);
    v_foc  = wsum(v_foc);
    if (lane == 0) {
        atomicAdd(&sh_scal[0], v_wnll);
        atomicAdd(&sh_scal[1], v_foc);
    }
#pragma unroll
    for (int c = 0; c < NCLS; ++c) {
        const float v = wsum(psum[c]);
        if (lane == c) atomicAdd(&sh_psum[c], v);
    }

    __syncthreads();

    // ---- one global atomic per class per block ----
    if (tid < NCLS) {
        atomicAdd(&ws[2 + tid],            sh_inter[tid]);
        atomicAdd(&ws[2 + NCLS + tid],     sh_psum[tid]);
        atomicAdd(&ws[2 + 2 * NCLS + tid], sh_cnt[tid]);
    } else if (tid >= 64 && tid < 66) {
        atomicAdd(&ws[tid - 64], sh_scal[tid - 64]);
    }
}

__global__ void focal_dice_final(const float* __restrict__ ws,
                                 const float* __restrict__ cw,
                                 float*       __restrict__ out)
{
    if (threadIdx.x == 0 && blockIdx.x == 0) {
        float sum_w = 0.f;
        for (int c = 0; c < NCLS; ++c) sum_w += cw[c] * ws[2 + 2 * NCLS + c];
        const float ce    = ws[0] / sum_w;
        const float focal = ws[1] * (1.f / (float)NPIX);
        float cwsum = 0.f;
        for (int c = 0; c < NCLS; ++c) cwsum += cw[c];
        const float inv = 1.f / fmaxf(cwsum, 1e-8f);
        float dsum = 0.f;
        for (int c = 0; c < NCLS; ++c) {
            const float I   = ws[2 + c];
            const float S   = ws[2 + NCLS + c];
            const float cnt = ws[2 + 2 * NCLS + c];
            const float dice = (2.f * I + 1.f) / (S + cnt + 1.f);
            dsum += dice * cw[c] * inv;
        }
        out[0] = 0.4f * ce + 0.3f * focal + 0.3f * (1.f - dsum);
    }
}

extern "C" void kernel_launch(void* const* d_in, const int* in_sizes, int n_in,
                              void* d_out, int out_size, void* d_ws, size_t ws_size,
                              hipStream_t stream)
{
    const float* logits = (const float*)d_in[0];
    const int*   target = (const int*)d_in[1];
    const float* cw     = (const float*)d_in[2];
    const float* fa     = (const float*)d_in[3];
    float* ws  = (float*)d_ws;
    float* out = (float*)d_out;

    hipMemsetAsync(d_ws, 0, (2 + 3 * NCLS) * sizeof(float), stream);
    focal_dice_main<<<BLOCKS, THREADS, 0, stream>>>(logits, target, cw, fa, ws);
    focal_dice_final<<<1, 64, 0, stream>>>(ws, cw, out);
}